// Round 14
// baseline (546.607 us; speedup 1.0000x reference)
//
#include <hip/hip_runtime.h>
#include <hip/hip_bf16.h>
#include <stdint.h>

#define D_IN 128
#define D_H 256
#define NLAYERS 5

typedef __bf16 bf16x8 __attribute__((ext_vector_type(8)));
typedef float f32x4 __attribute__((ext_vector_type(4)));
typedef unsigned short u16x8 __attribute__((ext_vector_type(8)));

// LDS tile row stride in ushorts: 260 u16 = 520 B; 130 dwords, 130%32==2 ->
// consecutive rows spread across banks (measured ~0 conflicts).
#define MID_STRIDE 260

__device__ inline unsigned short bfbits(float f) {
  __hip_bfloat16 h = __float2bfloat16(f);
  unsigned short s;
  __builtin_memcpy(&s, &h, 2);
  return s;
}

__device__ inline unsigned packbf(float lo, float hi) {
  return (unsigned)bfbits(lo) | ((unsigned)bfbits(hi) << 16);
}

// u holds 2 bf16 (lo in bits 0..15). Accumulate both into a,b.
__device__ inline void addbf2(float& a, float& b, unsigned u) {
  a += __uint_as_float(u << 16);
  b += __uint_as_float(u & 0xffff0000u);
}

__device__ inline void addbf2s(float& a, float& b, unsigned u, float s) {
  a += s * __uint_as_float(u << 16);
  b += s * __uint_as_float(u & 0xffff0000u);
}

// cast x (nx floats) and the 4 weight tensors to bf16, one launch
__global__ void conv_inputs(const float* __restrict__ x, const float* __restrict__ a,
                            const float* __restrict__ b, const float* __restrict__ c,
                            const float* __restrict__ d,
                            __hip_bfloat16* __restrict__ xb,
                            __hip_bfloat16* __restrict__ wb, int nx) {
  int gid = blockIdx.x * blockDim.x + threadIdx.x;
  if (gid < nx) {
    xb[gid] = __float2bfloat16(x[gid]);
    return;
  }
  gid -= nx;
  if (gid >= 622592) return;
  float v;
  if (gid < 32768) v = a[gid];
  else if (gid < 98304) v = b[gid - 32768];
  else if (gid < 360448) v = c[gid - 98304];
  else v = d[gid - 360448];
  wb[gid] = __float2bfloat16(v);
}

// ---- CSR build (XCD-affine dst-partitioned to kill line ping-pong) ----
// grid = 8 ranges x CHUNKS blocks; block (r=bid&7, chunk=bid>>3) reads its
// ei chunk and only touches deg/csr entries with dst in range r. With the
// round-robin bid->XCD mapping, atomics/writes stay in one XCD's L2.
#define CSR_CHUNKS 128

__global__ __launch_bounds__(256) void hist_kernel(const int* __restrict__ ei, int E,
                                                   int* __restrict__ deg, int N) {
  const int r = blockIdx.x & 7;
  const int chunk = blockIdx.x >> 3;
  const int rsize = (N + 7) >> 3;
  const int lo = r * rsize;
  const int hi = (lo + rsize < N) ? lo + rsize : N;
  const int stride = CSR_CHUNKS * 256;
  for (int e = chunk * 256 + threadIdx.x; e < E; e += stride) {
    int d = ei[E + e];
    if (d >= lo && d < hi) atomicAdd(&deg[d], 1);
  }
}

__global__ __launch_bounds__(256) void fill_kernel(const int* __restrict__ ei, int E,
                                                   const int* __restrict__ row_start,
                                                   int* __restrict__ cursor,
                                                   int* __restrict__ csr, int N) {
  const int r = blockIdx.x & 7;
  const int chunk = blockIdx.x >> 3;
  const int rsize = (N + 7) >> 3;
  const int lo = r * rsize;
  const int hi = (lo + rsize < N) ? lo + rsize : N;
  const int stride = CSR_CHUNKS * 256;
  for (int e = chunk * 256 + threadIdx.x; e < E; e += stride) {
    int d = ei[E + e];
    if (d >= lo && d < hi) {
      int p = atomicAdd(&cursor[d], 1);
      csr[row_start[d] + p] = ei[e];
    }
  }
}

__global__ __launch_bounds__(256) void block_sums(const int* __restrict__ deg,
                                                  int* __restrict__ bsum, int N) {
  int t = threadIdx.x;
  int idx = blockIdx.x * 1024 + t * 4;
  int4 v = {0, 0, 0, 0};
  if (idx + 3 < N) v = *reinterpret_cast<const int4*>(deg + idx);
  else {
    if (idx + 0 < N) v.x = deg[idx + 0];
    if (idx + 1 < N) v.y = deg[idx + 1];
    if (idx + 2 < N) v.z = deg[idx + 2];
    if (idx + 3 < N) v.w = deg[idx + 3];
  }
  int s = v.x + v.y + v.z + v.w;
#pragma unroll
  for (int off = 32; off > 0; off >>= 1) s += __shfl_down(s, off);
  __shared__ int ws[4];
  int lane = t & 63, w = t >> 6;
  if (lane == 0) ws[w] = s;
  __syncthreads();
  if (t == 0) bsum[blockIdx.x] = ws[0] + ws[1] + ws[2] + ws[3];
}

// full exclusive scan -> row_start; block offset computed in-kernel from the
// RAW per-block sums (nb <= 64 blocks, one wave-reduce) - no scan_bsums pass.
__global__ __launch_bounds__(256) void scan_apply(const int* __restrict__ deg,
                                                  const int* __restrict__ bsum,
                                                  int* __restrict__ row_start, int N) {
  __shared__ int woff[4];
  __shared__ int boff_sh;
  int t = threadIdx.x;
  // block offset = sum of bsum[j] for j < blockIdx.x  (bsum is raw sums)
  if (t < 64) {
    int v = (t < blockIdx.x) ? bsum[t] : 0;
#pragma unroll
    for (int off = 32; off > 0; off >>= 1) v += __shfl_down(v, off);
    if (t == 0) boff_sh = v;
  }
  int idx = blockIdx.x * 1024 + t * 4;
  int4 v = {0, 0, 0, 0};
  if (idx + 3 < N) v = *reinterpret_cast<const int4*>(deg + idx);
  else {
    if (idx + 0 < N) v.x = deg[idx + 0];
    if (idx + 1 < N) v.y = deg[idx + 1];
    if (idx + 2 < N) v.z = deg[idx + 2];
    if (idx + 3 < N) v.w = deg[idx + 3];
  }
  int s = v.x + v.y + v.z + v.w;
  int lane = t & 63, w = t >> 6;
  int sc = s;
#pragma unroll
  for (int off = 1; off < 64; off <<= 1) {
    int u = __shfl_up(sc, off);
    if (lane >= off) sc += u;
  }
  if (lane == 63) woff[w] = sc;
  __syncthreads();
  int boff = boff_sh;
#pragma unroll
  for (int i = 0; i < 4; ++i)
    if (i < w) boff += woff[i];
  int ex = boff + sc - s;
  if (idx + 3 < N) {
    int4 o;
    o.x = ex;
    o.y = ex + v.x;
    o.z = ex + v.x + v.y;
    o.w = ex + v.x + v.y + v.z;
    *reinterpret_cast<int4*>(row_start + idx) = o;
  } else {
    if (idx + 0 < N) row_start[idx + 0] = ex;
    if (idx + 1 < N) row_start[idx + 1] = ex + v.x;
    if (idx + 2 < N) row_start[idx + 2] = ex + v.x + v.y;
    if (idx + 3 < N) row_start[idx + 3] = ex + v.x + v.y + v.z;
  }
}

// ---- aggregation: pre[n] = bf16( (1+eps)*h[n] + sum_{s in in(n)} h[s] ) ----
// All-bf16 input. Half-wave (32 lanes) per node; indices broadcast via shfl;
// 8 rows in flight.
template <int D>
__global__ __launch_bounds__(256) void aggregate(const unsigned short* __restrict__ hb,
                                                 const int* __restrict__ csr,
                                                 const int* __restrict__ row_start,
                                                 const int* __restrict__ deg,
                                                 const float* __restrict__ eps_all,
                                                 int layer,
                                                 unsigned short* __restrict__ pre,
                                                 int N) {
  constexpr int PL = D / 32;  // ushorts per lane: 4 or 8
  const int half = threadIdx.x >> 5;
  const int lane = threadIdx.x & 31;
  const int node = blockIdx.x * 8 + half;
  if (node >= N) return;

  const int start = row_start[node];
  const int cnt = deg[node];
  const float epsv = 1.0f + eps_all[layer];

  float acc[PL];
#pragma unroll
  for (int j = 0; j < PL; ++j) acc[j] = 0.0f;

  if (D == 256) {
    uint4 su = *reinterpret_cast<const uint4*>(hb + (size_t)node * D + lane * 8);
    for (int base = 0; base < cnt; base += 32) {
      int m = cnt - base;
      if (m > 32) m = 32;
      int idx = (lane < m) ? csr[start + base + lane] : 0;
      int i = 0;
      for (; i + 8 <= m; i += 8) {
        uint4 q[8];
#pragma unroll
        for (int r = 0; r < 8; ++r) {
          int s = __shfl(idx, i + r, 32);
          q[r] = *reinterpret_cast<const uint4*>(hb + (size_t)s * D + lane * 8);
        }
#pragma unroll
        for (int r = 0; r < 8; ++r) {
          addbf2(acc[0], acc[1], q[r].x);
          addbf2(acc[2], acc[3], q[r].y);
          addbf2(acc[4], acc[5], q[r].z);
          addbf2(acc[6], acc[7], q[r].w);
        }
      }
      for (; i + 4 <= m; i += 4) {
        uint4 q[4];
#pragma unroll
        for (int r = 0; r < 4; ++r) {
          int s = __shfl(idx, i + r, 32);
          q[r] = *reinterpret_cast<const uint4*>(hb + (size_t)s * D + lane * 8);
        }
#pragma unroll
        for (int r = 0; r < 4; ++r) {
          addbf2(acc[0], acc[1], q[r].x);
          addbf2(acc[2], acc[3], q[r].y);
          addbf2(acc[4], acc[5], q[r].z);
          addbf2(acc[6], acc[7], q[r].w);
        }
      }
      for (; i < m; ++i) {
        int s = __shfl(idx, i, 32);
        uint4 q = *reinterpret_cast<const uint4*>(hb + (size_t)s * D + lane * 8);
        addbf2(acc[0], acc[1], q.x);
        addbf2(acc[2], acc[3], q.y);
        addbf2(acc[4], acc[5], q.z);
        addbf2(acc[6], acc[7], q.w);
      }
    }
    addbf2s(acc[0], acc[1], su.x, epsv);
    addbf2s(acc[2], acc[3], su.y, epsv);
    addbf2s(acc[4], acc[5], su.z, epsv);
    addbf2s(acc[6], acc[7], su.w, epsv);
    uint4 o;
    o.x = packbf(acc[0], acc[1]);
    o.y = packbf(acc[2], acc[3]);
    o.z = packbf(acc[4], acc[5]);
    o.w = packbf(acc[6], acc[7]);
    *reinterpret_cast<uint4*>(pre + (size_t)node * D + lane * 8) = o;
  } else {  // D == 128
    uint2 su = *reinterpret_cast<const uint2*>(hb + (size_t)node * D + lane * 4);
    for (int base = 0; base < cnt; base += 32) {
      int m = cnt - base;
      if (m > 32) m = 32;
      int idx = (lane < m) ? csr[start + base + lane] : 0;
      int i = 0;
      for (; i + 8 <= m; i += 8) {
        uint2 q[8];
#pragma unroll
        for (int r = 0; r < 8; ++r) {
          int s = __shfl(idx, i + r, 32);
          q[r] = *reinterpret_cast<const uint2*>(hb + (size_t)s * D + lane * 4);
        }
#pragma unroll
        for (int r = 0; r < 8; ++r) {
          addbf2(acc[0], acc[1], q[r].x);
          addbf2(acc[2], acc[3], q[r].y);
        }
      }
      for (; i + 4 <= m; i += 4) {
        uint2 q[4];
#pragma unroll
        for (int r = 0; r < 4; ++r) {
          int s = __shfl(idx, i + r, 32);
          q[r] = *reinterpret_cast<const uint2*>(hb + (size_t)s * D + lane * 4);
        }
#pragma unroll
        for (int r = 0; r < 4; ++r) {
          addbf2(acc[0], acc[1], q[r].x);
          addbf2(acc[2], acc[3], q[r].y);
        }
      }
      for (; i < m; ++i) {
        int s = __shfl(idx, i, 32);
        uint2 q = *reinterpret_cast<const uint2*>(hb + (size_t)s * D + lane * 4);
        addbf2(acc[0], acc[1], q.x);
        addbf2(acc[2], acc[3], q.y);
      }
    }
    addbf2s(acc[0], acc[1], su.x, epsv);
    addbf2s(acc[2], acc[3], su.y, epsv);
    uint2 o;
    o.x = packbf(acc[0], acc[1]);
    o.y = packbf(acc[2], acc[3]);
    *reinterpret_cast<uint2*>(pre + (size_t)node * D + lane * 4) = o;
  }
}

// ---- producer-consumer fused MLP: out = relu( relu(A@W0.T+b0) @ W1.T + b1 ) ----
// Block = 512 thr = 8 waves, one block per CU (grid 256). 64-row chunks,
// processed as 2x 32-row subtiles per buffer -> HALF the barriers of the
// 32-row version (the per-iteration __syncthreads was the dominant cost).
// Waves 0-3 (producers): W0 quarter in registers; load A frags, MFMA, write
//   mid=relu(.+b0) into the double-buffered LDS tile.
// Waves 4-7 (consumers): W1 quarter in registers; MFMA the LDS tile, store.
// mfma_f32_16x16x32_bf16 frag maps: A/B row/col = lane&15, k = (lane>>4)*8+j;
// C/D: col = lane&15, row = (lane>>4)*4 + reg.
template <int K0, bool OUT_BF16>
__global__ __launch_bounds__(512, 2) void mlp_fused(
    const unsigned short* __restrict__ Ap, const __hip_bfloat16* __restrict__ W0p,
    const float* __restrict__ b0, const __hip_bfloat16* __restrict__ W1p,
    const float* __restrict__ b1, void* __restrict__ Outp, int Nrows) {
  __shared__ unsigned short midb[2][64 * MID_STRIDE];  // 66.6 KB

  constexpr int NK0 = K0 / 32;
  constexpr int NK1 = D_H / 32;
  const int tid = threadIdx.x;
  const int wid = tid >> 6;        // 0..7
  const bool prod = (wid < 4);
  const int cg = wid & 3;          // col-group
  const int lane = tid & 63;
  const int l15 = lane & 15;
  const int kg = lane >> 4;
  const int col0 = cg * 64;
  const int nch = (Nrows + 63) >> 6;

  // register-resident W quarter + bias
  bf16x8 wfr[NK1][4];
  float bv[4];
  if (prod) {
    const unsigned short* Ws = (const unsigned short*)W0p;
#pragma unroll
    for (int ct = 0; ct < 4; ++ct) {
      const unsigned short* wrow = Ws + (size_t)(col0 + ct * 16 + l15) * K0 + kg * 8;
#pragma unroll
      for (int kk = 0; kk < NK0; ++kk)
        wfr[kk][ct] = *reinterpret_cast<const bf16x8*>(wrow + kk * 32);
      bv[ct] = b0[col0 + ct * 16 + l15];
    }
  } else {
    const unsigned short* Ws = (const unsigned short*)W1p;
#pragma unroll
    for (int ct = 0; ct < 4; ++ct) {
      const unsigned short* wrow = Ws + (size_t)(col0 + ct * 16 + l15) * D_H + kg * 8;
#pragma unroll
      for (int kk = 0; kk < NK1; ++kk)
        wfr[kk][ct] = *reinterpret_cast<const bf16x8*>(wrow + kk * 32);
      bv[ct] = b1[col0 + ct * 16 + l15];
    }
  }

  auto produce = [&](int c, unsigned short* buf) {
#pragma unroll
    for (int sub = 0; sub < 2; ++sub) {
      const int r0 = (c << 6) + sub * 32;
      bf16x8 afr[NK0][2];
#pragma unroll
      for (int rt = 0; rt < 2; ++rt) {
        int row = r0 + rt * 16 + l15;
        if (row > Nrows - 1) row = Nrows - 1;  // clamp: dup rows feed masked C
        const unsigned short* ar = Ap + (size_t)row * K0 + kg * 8;
#pragma unroll
        for (int kk = 0; kk < NK0; ++kk)
          afr[kk][rt] = *reinterpret_cast<const bf16x8*>(ar + kk * 32);
      }
      f32x4 acc[2][4];
#pragma unroll
      for (int rt = 0; rt < 2; ++rt)
#pragma unroll
        for (int ct = 0; ct < 4; ++ct) acc[rt][ct] = 0.0f;
#pragma unroll
      for (int kk = 0; kk < NK0; ++kk)
#pragma unroll
        for (int rt = 0; rt < 2; ++rt)
#pragma unroll
          for (int ct = 0; ct < 4; ++ct)
            acc[rt][ct] = __builtin_amdgcn_mfma_f32_16x16x32_bf16(
                afr[kk][rt], wfr[kk][ct], acc[rt][ct], 0, 0, 0);
#pragma unroll
      for (int ct = 0; ct < 4; ++ct) {
        int col = col0 + ct * 16 + l15;
#pragma unroll
        for (int rt = 0; rt < 2; ++rt)
#pragma unroll
          for (int i = 0; i < 4; ++i) {
            int row_l = sub * 32 + rt * 16 + kg * 4 + i;
            buf[row_l * MID_STRIDE + col] =
                bfbits(fmaxf(acc[rt][ct][i] + bv[ct], 0.0f));
          }
      }
    }
  };

  auto consume = [&](int c, const unsigned short* buf) {
#pragma unroll
    for (int sub = 0; sub < 2; ++sub) {
      const int r0 = (c << 6) + sub * 32;
      f32x4 acc[2][4];
#pragma unroll
      for (int rt = 0; rt < 2; ++rt)
#pragma unroll
        for (int ct = 0; ct < 4; ++ct) acc[rt][ct] = 0.0f;
#pragma unroll
      for (int kk = 0; kk < NK1; ++kk) {
        bf16x8 mfr[2];
#pragma unroll
        for (int rt = 0; rt < 2; ++rt)
          mfr[rt] = *reinterpret_cast<const bf16x8*>(
              buf + (sub * 32 + rt * 16 + l15) * MID_STRIDE + kk * 32 + kg * 8);
#pragma unroll
        for (int rt = 0; rt < 2; ++rt)
#pragma unroll
          for (int ct = 0; ct < 4; ++ct)
            acc[rt][ct] = __builtin_amdgcn_mfma_f32_16x16x32_bf16(
                mfr[rt], wfr[kk][ct], acc[rt][ct], 0, 0, 0);
      }
#pragma unroll
      for (int ct = 0; ct < 4; ++ct) {
        int col = col0 + ct * 16 + l15;
#pragma unroll
        for (int rt = 0; rt < 2; ++rt)
#pragma unroll
          for (int i = 0; i < 4; ++i) {
            int row = r0 + rt * 16 + kg * 4 + i;
            if (row < Nrows) {
              float v = fmaxf(acc[rt][ct][i] + bv[ct], 0.0f);
              if (OUT_BF16)
                ((__hip_bfloat16*)Outp)[(size_t)row * D_H + col] = __float2bfloat16(v);
              else
                ((float*)Outp)[(size_t)row * D_H + col] = v;
            }
          }
      }
    }
  };

  int c_pr = blockIdx.x;
  int c_co = blockIdx.x;
  int pb = 0;
  if (prod && c_pr < nch) produce(c_pr, midb[0]);
  __syncthreads();
  c_pr += gridDim.x;
  while (c_co < nch) {
    if (prod) {
      if (c_pr < nch) produce(c_pr, midb[pb ^ 1]);
    } else {
      consume(c_co, midb[pb]);
    }
    __syncthreads();
    pb ^= 1;
    c_pr += gridDim.x;
    c_co += gridDim.x;
  }
}

extern "C" void kernel_launch(void* const* d_in, const int* in_sizes, int n_in,
                              void* d_out, int out_size, void* d_ws, size_t ws_size,
                              hipStream_t stream) {
  const float* x = (const float*)d_in[0];
  const int* ei = (const int*)d_in[1];  // [2, E]: row0 = src, row1 = dst
  const float* eps_all = (const float*)d_in[2];
  const float* w0_l0 = (const float*)d_in[3];
  const float* b0_l0 = (const float*)d_in[4];
  const float* w1_l0 = (const float*)d_in[5];
  const float* b1_l0 = (const float*)d_in[6];
  const float* w0_rest = (const float*)d_in[7];
  const float* b0_rest = (const float*)d_in[8];
  const float* w1_rest = (const float*)d_in[9];
  const float* b1_rest = (const float*)d_in[10];

  const int N = in_sizes[0] / D_IN;  // 50000
  const int E = in_sizes[1] / 2;     // 800000
  const int NX = N * D_IN;           // x elements

  char* ws = (char*)d_ws;
  const size_t node_bf = (size_t)N * D_H * sizeof(unsigned short);  // 25.6 MB
  unsigned short* h = (unsigned short*)ws;                // layer outputs
  unsigned short* pre = (unsigned short*)(ws + node_bf);  // aggregate out
  unsigned short* xb = (unsigned short*)(ws + 2 * node_bf);  // x cast to bf16
  char* p = ws + 2 * node_bf + (size_t)NX * sizeof(unsigned short);
  __hip_bfloat16* wbf = (__hip_bfloat16*)p;
  p += 622592 * sizeof(__hip_bfloat16);
  int* deg = (int*)p;           // [N]
  int* cursor = deg + N;        // [N]
  int* row_start = cursor + N;  // [N]
  int* bsum = row_start + N;    // [64]
  int* csr = bsum + 64;         // [E]

  __hip_bfloat16* w0_l0_bf = wbf;
  __hip_bfloat16* w1_l0_bf = wbf + 32768;
  __hip_bfloat16* w0_rest_bf = wbf + 98304;
  __hip_bfloat16* w1_rest_bf = w0_rest_bf + 262144;

  conv_inputs<<<(NX + 622592 + 255) / 256, 256, 0, stream>>>(
      x, w0_l0, w1_l0, w0_rest, w1_rest, (__hip_bfloat16*)xb, wbf, NX);

  // CSR build
  const int nb = (N + 1023) / 1024;  // 49
  hipMemsetAsync(deg, 0, (size_t)2 * N * sizeof(int), stream);  // deg + cursor
  hist_kernel<<<8 * CSR_CHUNKS, 256, 0, stream>>>(ei, E, deg, N);
  block_sums<<<nb, 256, 0, stream>>>(deg, bsum, N);
  scan_apply<<<nb, 256, 0, stream>>>(deg, bsum, row_start, N);
  fill_kernel<<<8 * CSR_CHUNKS, 256, 0, stream>>>(ei, E, row_start, cursor, csr, N);

  const int mlpGrid = 256;  // one 8-wave block per CU
  const int aggBlocks = (N + 7) / 8;

  for (int layer = 0; layer < NLAYERS; ++layer) {
    const __hip_bfloat16* w0 =
        (layer == 0) ? w0_l0_bf : w0_rest_bf + (size_t)(layer - 1) * 65536;
    const float* b0 = (layer == 0) ? b0_l0 : b0_rest + (size_t)(layer - 1) * 256;
    const __hip_bfloat16* w1 =
        (layer == 0) ? w1_l0_bf : w1_rest_bf + (size_t)(layer - 1) * 65536;
    const float* b1 = (layer == 0) ? b1_l0 : b1_rest + (size_t)(layer - 1) * 256;

    if (layer == 0) {
      aggregate<D_IN><<<aggBlocks, 256, 0, stream>>>(xb, csr, row_start, deg,
                                                     eps_all, layer, pre, N);
      mlp_fused<D_IN, true><<<mlpGrid, 512, 0, stream>>>(pre, w0, b0, w1, b1, h, N);
    } else {
      aggregate<D_H><<<aggBlocks, 256, 0, stream>>>(h, csr, row_start, deg,
                                                    eps_all, layer, pre, N);
      if (layer == NLAYERS - 1)
        mlp_fused<D_H, false><<<mlpGrid, 512, 0, stream>>>(pre, w0, b0, w1, b1,
                                                           d_out, N);
      else
        mlp_fused<D_H, true><<<mlpGrid, 512, 0, stream>>>(pre, w0, b0, w1, b1, h, N);
    }
  }
}

// Round 15
// 518.551 us; speedup vs baseline: 1.0541x; 1.0541x over previous
//
#include <hip/hip_runtime.h>
#include <hip/hip_bf16.h>
#include <stdint.h>

#define D_IN 128
#define D_H 256
#define NLAYERS 5

typedef __bf16 bf16x8 __attribute__((ext_vector_type(8)));
typedef float f32x4 __attribute__((ext_vector_type(4)));
typedef unsigned short u16x8 __attribute__((ext_vector_type(8)));

// LDS tile row stride in ushorts: 260 u16 = 520 B; 130 dwords, 130%32==2 ->
// consecutive rows spread across banks (measured ~0 conflicts).
#define MID_STRIDE 260

__device__ inline unsigned short bfbits(float f) {
  __hip_bfloat16 h = __float2bfloat16(f);
  unsigned short s;
  __builtin_memcpy(&s, &h, 2);
  return s;
}

__device__ inline unsigned packbf(float lo, float hi) {
  return (unsigned)bfbits(lo) | ((unsigned)bfbits(hi) << 16);
}

// u holds 2 bf16 (lo in bits 0..15). Accumulate both into a,b.
__device__ inline void addbf2(float& a, float& b, unsigned u) {
  a += __uint_as_float(u << 16);
  b += __uint_as_float(u & 0xffff0000u);
}

__device__ inline void addbf2s(float& a, float& b, unsigned u, float s) {
  a += s * __uint_as_float(u << 16);
  b += s * __uint_as_float(u & 0xffff0000u);
}

// cast x (nx floats) and the 4 weight tensors to bf16, one launch
__global__ void conv_inputs(const float* __restrict__ x, const float* __restrict__ a,
                            const float* __restrict__ b, const float* __restrict__ c,
                            const float* __restrict__ d,
                            __hip_bfloat16* __restrict__ xb,
                            __hip_bfloat16* __restrict__ wb, int nx) {
  int gid = blockIdx.x * blockDim.x + threadIdx.x;
  if (gid < nx) {
    xb[gid] = __float2bfloat16(x[gid]);
    return;
  }
  gid -= nx;
  if (gid >= 622592) return;
  float v;
  if (gid < 32768) v = a[gid];
  else if (gid < 98304) v = b[gid - 32768];
  else if (gid < 360448) v = c[gid - 98304];
  else v = d[gid - 360448];
  wb[gid] = __float2bfloat16(v);
}

// ---- CSR build (XCD-affine dst-partitioned to kill line ping-pong) ----
#define CSR_CHUNKS 128

__global__ __launch_bounds__(256) void hist_kernel(const int* __restrict__ ei, int E,
                                                   int* __restrict__ deg, int N) {
  const int r = blockIdx.x & 7;
  const int chunk = blockIdx.x >> 3;
  const int rsize = (N + 7) >> 3;
  const int lo = r * rsize;
  const int hi = (lo + rsize < N) ? lo + rsize : N;
  const int stride = CSR_CHUNKS * 256;
  for (int e = chunk * 256 + threadIdx.x; e < E; e += stride) {
    int d = ei[E + e];
    if (d >= lo && d < hi) atomicAdd(&deg[d], 1);
  }
}

__global__ __launch_bounds__(256) void fill_kernel(const int* __restrict__ ei, int E,
                                                   const int* __restrict__ row_start,
                                                   int* __restrict__ cursor,
                                                   int* __restrict__ csr, int N) {
  const int r = blockIdx.x & 7;
  const int chunk = blockIdx.x >> 3;
  const int rsize = (N + 7) >> 3;
  const int lo = r * rsize;
  const int hi = (lo + rsize < N) ? lo + rsize : N;
  const int stride = CSR_CHUNKS * 256;
  for (int e = chunk * 256 + threadIdx.x; e < E; e += stride) {
    int d = ei[E + e];
    if (d >= lo && d < hi) {
      int p = atomicAdd(&cursor[d], 1);
      csr[row_start[d] + p] = ei[e];
    }
  }
}

__global__ __launch_bounds__(256) void block_sums(const int* __restrict__ deg,
                                                  int* __restrict__ bsum, int N) {
  int t = threadIdx.x;
  int idx = blockIdx.x * 1024 + t * 4;
  int4 v = {0, 0, 0, 0};
  if (idx + 3 < N) v = *reinterpret_cast<const int4*>(deg + idx);
  else {
    if (idx + 0 < N) v.x = deg[idx + 0];
    if (idx + 1 < N) v.y = deg[idx + 1];
    if (idx + 2 < N) v.z = deg[idx + 2];
    if (idx + 3 < N) v.w = deg[idx + 3];
  }
  int s = v.x + v.y + v.z + v.w;
#pragma unroll
  for (int off = 32; off > 0; off >>= 1) s += __shfl_down(s, off);
  __shared__ int ws[4];
  int lane = t & 63, w = t >> 6;
  if (lane == 0) ws[w] = s;
  __syncthreads();
  if (t == 0) bsum[blockIdx.x] = ws[0] + ws[1] + ws[2] + ws[3];
}

// full exclusive scan -> row_start; block offset computed in-kernel from the
// RAW per-block sums (nb <= 64 blocks, one wave-reduce) - no scan_bsums pass.
__global__ __launch_bounds__(256) void scan_apply(const int* __restrict__ deg,
                                                  const int* __restrict__ bsum,
                                                  int* __restrict__ row_start, int N) {
  __shared__ int woff[4];
  __shared__ int boff_sh;
  int t = threadIdx.x;
  if (t < 64) {
    int v = (t < blockIdx.x) ? bsum[t] : 0;
#pragma unroll
    for (int off = 32; off > 0; off >>= 1) v += __shfl_down(v, off);
    if (t == 0) boff_sh = v;
  }
  int idx = blockIdx.x * 1024 + t * 4;
  int4 v = {0, 0, 0, 0};
  if (idx + 3 < N) v = *reinterpret_cast<const int4*>(deg + idx);
  else {
    if (idx + 0 < N) v.x = deg[idx + 0];
    if (idx + 1 < N) v.y = deg[idx + 1];
    if (idx + 2 < N) v.z = deg[idx + 2];
    if (idx + 3 < N) v.w = deg[idx + 3];
  }
  int s = v.x + v.y + v.z + v.w;
  int lane = t & 63, w = t >> 6;
  int sc = s;
#pragma unroll
  for (int off = 1; off < 64; off <<= 1) {
    int u = __shfl_up(sc, off);
    if (lane >= off) sc += u;
  }
  if (lane == 63) woff[w] = sc;
  __syncthreads();
  int boff = boff_sh;
#pragma unroll
  for (int i = 0; i < 4; ++i)
    if (i < w) boff += woff[i];
  int ex = boff + sc - s;
  if (idx + 3 < N) {
    int4 o;
    o.x = ex;
    o.y = ex + v.x;
    o.z = ex + v.x + v.y;
    o.w = ex + v.x + v.y + v.z;
    *reinterpret_cast<int4*>(row_start + idx) = o;
  } else {
    if (idx + 0 < N) row_start[idx + 0] = ex;
    if (idx + 1 < N) row_start[idx + 1] = ex + v.x;
    if (idx + 2 < N) row_start[idx + 2] = ex + v.x + v.y;
    if (idx + 3 < N) row_start[idx + 3] = ex + v.x + v.y + v.z;
  }
}

// ---- aggregation: pre[n] = bf16( (1+eps)*h[n] + sum_{s in in(n)} h[s] ) ----
template <int D>
__global__ __launch_bounds__(256) void aggregate(const unsigned short* __restrict__ hb,
                                                 const int* __restrict__ csr,
                                                 const int* __restrict__ row_start,
                                                 const int* __restrict__ deg,
                                                 const float* __restrict__ eps_all,
                                                 int layer,
                                                 unsigned short* __restrict__ pre,
                                                 int N) {
  constexpr int PL = D / 32;
  const int half = threadIdx.x >> 5;
  const int lane = threadIdx.x & 31;
  const int node = blockIdx.x * 8 + half;
  if (node >= N) return;

  const int start = row_start[node];
  const int cnt = deg[node];
  const float epsv = 1.0f + eps_all[layer];

  float acc[PL];
#pragma unroll
  for (int j = 0; j < PL; ++j) acc[j] = 0.0f;

  if (D == 256) {
    uint4 su = *reinterpret_cast<const uint4*>(hb + (size_t)node * D + lane * 8);
    for (int base = 0; base < cnt; base += 32) {
      int m = cnt - base;
      if (m > 32) m = 32;
      int idx = (lane < m) ? csr[start + base + lane] : 0;
      int i = 0;
      for (; i + 8 <= m; i += 8) {
        uint4 q[8];
#pragma unroll
        for (int r = 0; r < 8; ++r) {
          int s = __shfl(idx, i + r, 32);
          q[r] = *reinterpret_cast<const uint4*>(hb + (size_t)s * D + lane * 8);
        }
#pragma unroll
        for (int r = 0; r < 8; ++r) {
          addbf2(acc[0], acc[1], q[r].x);
          addbf2(acc[2], acc[3], q[r].y);
          addbf2(acc[4], acc[5], q[r].z);
          addbf2(acc[6], acc[7], q[r].w);
        }
      }
      for (; i + 4 <= m; i += 4) {
        uint4 q[4];
#pragma unroll
        for (int r = 0; r < 4; ++r) {
          int s = __shfl(idx, i + r, 32);
          q[r] = *reinterpret_cast<const uint4*>(hb + (size_t)s * D + lane * 8);
        }
#pragma unroll
        for (int r = 0; r < 4; ++r) {
          addbf2(acc[0], acc[1], q[r].x);
          addbf2(acc[2], acc[3], q[r].y);
          addbf2(acc[4], acc[5], q[r].z);
          addbf2(acc[6], acc[7], q[r].w);
        }
      }
      for (; i < m; ++i) {
        int s = __shfl(idx, i, 32);
        uint4 q = *reinterpret_cast<const uint4*>(hb + (size_t)s * D + lane * 8);
        addbf2(acc[0], acc[1], q.x);
        addbf2(acc[2], acc[3], q.y);
        addbf2(acc[4], acc[5], q.z);
        addbf2(acc[6], acc[7], q.w);
      }
    }
    addbf2s(acc[0], acc[1], su.x, epsv);
    addbf2s(acc[2], acc[3], su.y, epsv);
    addbf2s(acc[4], acc[5], su.z, epsv);
    addbf2s(acc[6], acc[7], su.w, epsv);
    uint4 o;
    o.x = packbf(acc[0], acc[1]);
    o.y = packbf(acc[2], acc[3]);
    o.z = packbf(acc[4], acc[5]);
    o.w = packbf(acc[6], acc[7]);
    *reinterpret_cast<uint4*>(pre + (size_t)node * D + lane * 8) = o;
  } else {  // D == 128
    uint2 su = *reinterpret_cast<const uint2*>(hb + (size_t)node * D + lane * 4);
    for (int base = 0; base < cnt; base += 32) {
      int m = cnt - base;
      if (m > 32) m = 32;
      int idx = (lane < m) ? csr[start + base + lane] : 0;
      int i = 0;
      for (; i + 8 <= m; i += 8) {
        uint2 q[8];
#pragma unroll
        for (int r = 0; r < 8; ++r) {
          int s = __shfl(idx, i + r, 32);
          q[r] = *reinterpret_cast<const uint2*>(hb + (size_t)s * D + lane * 4);
        }
#pragma unroll
        for (int r = 0; r < 8; ++r) {
          addbf2(acc[0], acc[1], q[r].x);
          addbf2(acc[2], acc[3], q[r].y);
        }
      }
      for (; i + 4 <= m; i += 4) {
        uint2 q[4];
#pragma unroll
        for (int r = 0; r < 4; ++r) {
          int s = __shfl(idx, i + r, 32);
          q[r] = *reinterpret_cast<const uint2*>(hb + (size_t)s * D + lane * 4);
        }
#pragma unroll
        for (int r = 0; r < 4; ++r) {
          addbf2(acc[0], acc[1], q[r].x);
          addbf2(acc[2], acc[3], q[r].y);
        }
      }
      for (; i < m; ++i) {
        int s = __shfl(idx, i, 32);
        uint2 q = *reinterpret_cast<const uint2*>(hb + (size_t)s * D + lane * 4);
        addbf2(acc[0], acc[1], q.x);
        addbf2(acc[2], acc[3], q.y);
      }
    }
    addbf2s(acc[0], acc[1], su.x, epsv);
    addbf2s(acc[2], acc[3], su.y, epsv);
    uint2 o;
    o.x = packbf(acc[0], acc[1]);
    o.y = packbf(acc[2], acc[3]);
    *reinterpret_cast<uint2*>(pre + (size_t)node * D + lane * 4) = o;
  }
}

// ---- producer-consumer fused MLP: out = relu( relu(A@W0.T+b0) @ W1.T + b1 ) ----
// Block = 512 thr = 8 waves, one block per CU (grid 256), 32-row chunks.
// Chunk index comes from a global work-stealing counter (one atomic by t0,
// broadcast via LDS at the already-required barrier) -> no static-stride tail.
// Waves 0-3 (producers): W0 quarter in regs; load A, MFMA, write mid to LDS.
// Waves 4-7 (consumers): W1 quarter in regs; MFMA LDS tile, store out.
template <int K0, bool OUT_BF16>
__global__ __launch_bounds__(512, 2) void mlp_fused(
    const unsigned short* __restrict__ Ap, const __hip_bfloat16* __restrict__ W0p,
    const float* __restrict__ b0, const __hip_bfloat16* __restrict__ W1p,
    const float* __restrict__ b1, void* __restrict__ Outp, int Nrows,
    int* __restrict__ work_ctr) {
  __shared__ unsigned short midb[2][32 * MID_STRIDE];  // 33.3 KB
  __shared__ int next_sh;

  constexpr int NK0 = K0 / 32;
  constexpr int NK1 = D_H / 32;
  const int tid = threadIdx.x;
  const int wid = tid >> 6;        // 0..7
  const bool prod = (wid < 4);
  const int cg = wid & 3;          // col-group
  const int lane = tid & 63;
  const int l15 = lane & 15;
  const int kg = lane >> 4;
  const int col0 = cg * 64;
  const int nch = (Nrows + 31) >> 5;

  // register-resident W quarter + bias
  bf16x8 wfr[NK1][4];
  float bv[4];
  if (prod) {
    const unsigned short* Ws = (const unsigned short*)W0p;
#pragma unroll
    for (int ct = 0; ct < 4; ++ct) {
      const unsigned short* wrow = Ws + (size_t)(col0 + ct * 16 + l15) * K0 + kg * 8;
#pragma unroll
      for (int kk = 0; kk < NK0; ++kk)
        wfr[kk][ct] = *reinterpret_cast<const bf16x8*>(wrow + kk * 32);
      bv[ct] = b0[col0 + ct * 16 + l15];
    }
  } else {
    const unsigned short* Ws = (const unsigned short*)W1p;
#pragma unroll
    for (int ct = 0; ct < 4; ++ct) {
      const unsigned short* wrow = Ws + (size_t)(col0 + ct * 16 + l15) * D_H + kg * 8;
#pragma unroll
      for (int kk = 0; kk < NK1; ++kk)
        wfr[kk][ct] = *reinterpret_cast<const bf16x8*>(wrow + kk * 32);
      bv[ct] = b1[col0 + ct * 16 + l15];
    }
  }

  auto produce = [&](int c, unsigned short* buf) {
    const int r0 = c << 5;
    bf16x8 afr[NK0][2];
#pragma unroll
    for (int rt = 0; rt < 2; ++rt) {
      int row = r0 + rt * 16 + l15;
      if (row > Nrows - 1) row = Nrows - 1;  // clamp: dup rows feed masked C
      const unsigned short* ar = Ap + (size_t)row * K0 + kg * 8;
#pragma unroll
      for (int kk = 0; kk < NK0; ++kk)
        afr[kk][rt] = *reinterpret_cast<const bf16x8*>(ar + kk * 32);
    }
    f32x4 acc[2][4];
#pragma unroll
    for (int rt = 0; rt < 2; ++rt)
#pragma unroll
      for (int ct = 0; ct < 4; ++ct) acc[rt][ct] = 0.0f;
#pragma unroll
    for (int kk = 0; kk < NK0; ++kk)
#pragma unroll
      for (int rt = 0; rt < 2; ++rt)
#pragma unroll
        for (int ct = 0; ct < 4; ++ct)
          acc[rt][ct] = __builtin_amdgcn_mfma_f32_16x16x32_bf16(
              afr[kk][rt], wfr[kk][ct], acc[rt][ct], 0, 0, 0);
#pragma unroll
    for (int ct = 0; ct < 4; ++ct) {
      int col = col0 + ct * 16 + l15;
#pragma unroll
      for (int rt = 0; rt < 2; ++rt)
#pragma unroll
        for (int i = 0; i < 4; ++i) {
          int row_l = rt * 16 + kg * 4 + i;
          buf[row_l * MID_STRIDE + col] = bfbits(fmaxf(acc[rt][ct][i] + bv[ct], 0.0f));
        }
    }
  };

  auto consume = [&](int c, const unsigned short* buf) {
    const int r0 = c << 5;
    f32x4 acc[2][4];
#pragma unroll
    for (int rt = 0; rt < 2; ++rt)
#pragma unroll
      for (int ct = 0; ct < 4; ++ct) acc[rt][ct] = 0.0f;
#pragma unroll
    for (int kk = 0; kk < NK1; ++kk) {
      bf16x8 mfr[2];
#pragma unroll
      for (int rt = 0; rt < 2; ++rt)
        mfr[rt] = *reinterpret_cast<const bf16x8*>(
            buf + (rt * 16 + l15) * MID_STRIDE + kk * 32 + kg * 8);
#pragma unroll
      for (int rt = 0; rt < 2; ++rt)
#pragma unroll
        for (int ct = 0; ct < 4; ++ct)
          acc[rt][ct] = __builtin_amdgcn_mfma_f32_16x16x32_bf16(
              mfr[rt], wfr[kk][ct], acc[rt][ct], 0, 0, 0);
    }
#pragma unroll
    for (int ct = 0; ct < 4; ++ct) {
      int col = col0 + ct * 16 + l15;
#pragma unroll
      for (int rt = 0; rt < 2; ++rt)
#pragma unroll
        for (int i = 0; i < 4; ++i) {
          int row = r0 + rt * 16 + kg * 4 + i;
          if (row < Nrows) {
            float v = fmaxf(acc[rt][ct][i] + bv[ct], 0.0f);
            if (OUT_BF16)
              ((__hip_bfloat16*)Outp)[(size_t)row * D_H + col] = __float2bfloat16(v);
            else
              ((float*)Outp)[(size_t)row * D_H + col] = v;
          }
        }
    }
  };

  // work-stealing pipeline: c_cur consumed this iter, c_nxt produced this iter
  if (tid == 0) next_sh = atomicAdd(work_ctr, 1);
  __syncthreads();
  int c_cur = next_sh;
  if (prod && c_cur < nch) produce(c_cur, midb[0]);
  if (tid == 0) next_sh = atomicAdd(work_ctr, 1);
  __syncthreads();
  int pb = 0;
  while (c_cur < nch) {
    int c_nxt = next_sh;
    if (prod) {
      if (c_nxt < nch) produce(c_nxt, midb[pb ^ 1]);
    } else {
      consume(c_cur, midb[pb]);
    }
    if (tid == 0 && c_nxt < nch) next_sh = atomicAdd(work_ctr, 1);
    __syncthreads();
    pb ^= 1;
    c_cur = c_nxt;
  }
}

__global__ void reset_ctrs(int* __restrict__ p, int n) {
  if (threadIdx.x < n) p[threadIdx.x] = 0;
}

extern "C" void kernel_launch(void* const* d_in, const int* in_sizes, int n_in,
                              void* d_out, int out_size, void* d_ws, size_t ws_size,
                              hipStream_t stream) {
  const float* x = (const float*)d_in[0];
  const int* ei = (const int*)d_in[1];  // [2, E]: row0 = src, row1 = dst
  const float* eps_all = (const float*)d_in[2];
  const float* w0_l0 = (const float*)d_in[3];
  const float* b0_l0 = (const float*)d_in[4];
  const float* w1_l0 = (const float*)d_in[5];
  const float* b1_l0 = (const float*)d_in[6];
  const float* w0_rest = (const float*)d_in[7];
  const float* b0_rest = (const float*)d_in[8];
  const float* w1_rest = (const float*)d_in[9];
  const float* b1_rest = (const float*)d_in[10];

  const int N = in_sizes[0] / D_IN;  // 50000
  const int E = in_sizes[1] / 2;     // 800000
  const int NX = N * D_IN;           // x elements

  char* ws = (char*)d_ws;
  const size_t node_bf = (size_t)N * D_H * sizeof(unsigned short);  // 25.6 MB
  unsigned short* h = (unsigned short*)ws;                // layer outputs
  unsigned short* pre = (unsigned short*)(ws + node_bf);  // aggregate out
  unsigned short* xb = (unsigned short*)(ws + 2 * node_bf);  // x cast to bf16
  char* p = ws + 2 * node_bf + (size_t)NX * sizeof(unsigned short);
  __hip_bfloat16* wbf = (__hip_bfloat16*)p;
  p += 622592 * sizeof(__hip_bfloat16);
  int* deg = (int*)p;           // [N]
  int* cursor = deg + N;        // [N]
  int* row_start = cursor + N;  // [N]
  int* bsum = row_start + N;    // [64]
  int* wctr = bsum + 64;        // [8] work-stealing counters
  int* csr = wctr + 8;          // [E]

  __hip_bfloat16* w0_l0_bf = wbf;
  __hip_bfloat16* w1_l0_bf = wbf + 32768;
  __hip_bfloat16* w0_rest_bf = wbf + 98304;
  __hip_bfloat16* w1_rest_bf = w0_rest_bf + 262144;

  conv_inputs<<<(NX + 622592 + 255) / 256, 256, 0, stream>>>(
      x, w0_l0, w1_l0, w0_rest, w1_rest, (__hip_bfloat16*)xb, wbf, NX);

  // CSR build
  const int nb = (N + 1023) / 1024;  // 49
  hipMemsetAsync(deg, 0, (size_t)2 * N * sizeof(int), stream);  // deg + cursor
  reset_ctrs<<<1, 64, 0, stream>>>(wctr, 8);
  hist_kernel<<<8 * CSR_CHUNKS, 256, 0, stream>>>(ei, E, deg, N);
  block_sums<<<nb, 256, 0, stream>>>(deg, bsum, N);
  scan_apply<<<nb, 256, 0, stream>>>(deg, bsum, row_start, N);
  fill_kernel<<<8 * CSR_CHUNKS, 256, 0, stream>>>(ei, E, row_start, cursor, csr, N);

  const int mlpGrid = 256;  // one 8-wave block per CU
  const int aggBlocks = (N + 7) / 8;

  for (int layer = 0; layer < NLAYERS; ++layer) {
    const __hip_bfloat16* w0 =
        (layer == 0) ? w0_l0_bf : w0_rest_bf + (size_t)(layer - 1) * 65536;
    const float* b0 = (layer == 0) ? b0_l0 : b0_rest + (size_t)(layer - 1) * 256;
    const __hip_bfloat16* w1 =
        (layer == 0) ? w1_l0_bf : w1_rest_bf + (size_t)(layer - 1) * 65536;
    const float* b1 = (layer == 0) ? b1_l0 : b1_rest + (size_t)(layer - 1) * 256;

    if (layer == 0) {
      aggregate<D_IN><<<aggBlocks, 256, 0, stream>>>(xb, csr, row_start, deg,
                                                     eps_all, layer, pre, N);
      mlp_fused<D_IN, true><<<mlpGrid, 512, 0, stream>>>(pre, w0, b0, w1, b1, h, N,
                                                         wctr + layer);
    } else {
      aggregate<D_H><<<aggBlocks, 256, 0, stream>>>(h, csr, row_start, deg,
                                                    eps_all, layer, pre, N);
      if (layer == NLAYERS - 1)
        mlp_fused<D_H, false><<<mlpGrid, 512, 0, stream>>>(pre, w0, b0, w1, b1,
                                                           d_out, N, wctr + layer);
      else
        mlp_fused<D_H, true><<<mlpGrid, 512, 0, stream>>>(pre, w0, b0, w1, b1, h, N,
                                                          wctr + layer);
    }
  }
}

// Round 16
// 507.807 us; speedup vs baseline: 1.0764x; 1.0212x over previous
//
#include <hip/hip_runtime.h>
#include <hip/hip_bf16.h>
#include <stdint.h>

#define D_IN 128
#define D_H 256
#define NLAYERS 5

typedef __bf16 bf16x8 __attribute__((ext_vector_type(8)));
typedef float f32x4 __attribute__((ext_vector_type(4)));
typedef unsigned short u16x8 __attribute__((ext_vector_type(8)));

// LDS tile row stride in ushorts: 260 u16 = 520 B; 130 dwords, 130%32==2 ->
// consecutive rows spread across banks (measured ~0 conflicts).
#define MID_STRIDE 260

__device__ inline unsigned short bfbits(float f) {
  __hip_bfloat16 h = __float2bfloat16(f);
  unsigned short s;
  __builtin_memcpy(&s, &h, 2);
  return s;
}

__device__ inline unsigned packbf(float lo, float hi) {
  return (unsigned)bfbits(lo) | ((unsigned)bfbits(hi) << 16);
}

// u holds 2 bf16 (lo in bits 0..15). Accumulate both into a,b.
__device__ inline void addbf2(float& a, float& b, unsigned u) {
  a += __uint_as_float(u << 16);
  b += __uint_as_float(u & 0xffff0000u);
}

__device__ inline void addbf2s(float& a, float& b, unsigned u, float s) {
  a += s * __uint_as_float(u << 16);
  b += s * __uint_as_float(u & 0xffff0000u);
}

// cast x (nx floats) and the 4 weight tensors to bf16, one launch
__global__ void conv_inputs(const float* __restrict__ x, const float* __restrict__ a,
                            const float* __restrict__ b, const float* __restrict__ c,
                            const float* __restrict__ d,
                            __hip_bfloat16* __restrict__ xb,
                            __hip_bfloat16* __restrict__ wb, int nx) {
  int gid = blockIdx.x * blockDim.x + threadIdx.x;
  if (gid < nx) {
    xb[gid] = __float2bfloat16(x[gid]);
    return;
  }
  gid -= nx;
  if (gid >= 622592) return;
  float v;
  if (gid < 32768) v = a[gid];
  else if (gid < 98304) v = b[gid - 32768];
  else if (gid < 360448) v = c[gid - 98304];
  else v = d[gid - 360448];
  wb[gid] = __float2bfloat16(v);
}

// ---- CSR build (XCD-affine dst-partitioned to kill line ping-pong) ----
#define CSR_CHUNKS 128

__global__ __launch_bounds__(256) void hist_kernel(const int* __restrict__ ei, int E,
                                                   int* __restrict__ deg, int N) {
  const int r = blockIdx.x & 7;
  const int chunk = blockIdx.x >> 3;
  const int rsize = (N + 7) >> 3;
  const int lo = r * rsize;
  const int hi = (lo + rsize < N) ? lo + rsize : N;
  const int stride = CSR_CHUNKS * 256;
  for (int e = chunk * 256 + threadIdx.x; e < E; e += stride) {
    int d = ei[E + e];
    if (d >= lo && d < hi) atomicAdd(&deg[d], 1);
  }
}

__global__ __launch_bounds__(256) void fill_kernel(const int* __restrict__ ei, int E,
                                                   const int* __restrict__ row_start,
                                                   int* __restrict__ cursor,
                                                   int* __restrict__ csr, int N) {
  const int r = blockIdx.x & 7;
  const int chunk = blockIdx.x >> 3;
  const int rsize = (N + 7) >> 3;
  const int lo = r * rsize;
  const int hi = (lo + rsize < N) ? lo + rsize : N;
  const int stride = CSR_CHUNKS * 256;
  for (int e = chunk * 256 + threadIdx.x; e < E; e += stride) {
    int d = ei[E + e];
    if (d >= lo && d < hi) {
      int p = atomicAdd(&cursor[d], 1);
      csr[row_start[d] + p] = ei[e];
    }
  }
}

__global__ __launch_bounds__(256) void block_sums(const int* __restrict__ deg,
                                                  int* __restrict__ bsum, int N) {
  int t = threadIdx.x;
  int idx = blockIdx.x * 1024 + t * 4;
  int4 v = {0, 0, 0, 0};
  if (idx + 3 < N) v = *reinterpret_cast<const int4*>(deg + idx);
  else {
    if (idx + 0 < N) v.x = deg[idx + 0];
    if (idx + 1 < N) v.y = deg[idx + 1];
    if (idx + 2 < N) v.z = deg[idx + 2];
    if (idx + 3 < N) v.w = deg[idx + 3];
  }
  int s = v.x + v.y + v.z + v.w;
#pragma unroll
  for (int off = 32; off > 0; off >>= 1) s += __shfl_down(s, off);
  __shared__ int ws[4];
  int lane = t & 63, w = t >> 6;
  if (lane == 0) ws[w] = s;
  __syncthreads();
  if (t == 0) bsum[blockIdx.x] = ws[0] + ws[1] + ws[2] + ws[3];
}

// full exclusive scan -> row_start; block offset computed in-kernel from the
// RAW per-block sums (nb <= 64 blocks, one wave-reduce) - no scan_bsums pass.
__global__ __launch_bounds__(256) void scan_apply(const int* __restrict__ deg,
                                                  const int* __restrict__ bsum,
                                                  int* __restrict__ row_start, int N) {
  __shared__ int woff[4];
  __shared__ int boff_sh;
  int t = threadIdx.x;
  if (t < 64) {
    int v = (t < blockIdx.x) ? bsum[t] : 0;
#pragma unroll
    for (int off = 32; off > 0; off >>= 1) v += __shfl_down(v, off);
    if (t == 0) boff_sh = v;
  }
  int idx = blockIdx.x * 1024 + t * 4;
  int4 v = {0, 0, 0, 0};
  if (idx + 3 < N) v = *reinterpret_cast<const int4*>(deg + idx);
  else {
    if (idx + 0 < N) v.x = deg[idx + 0];
    if (idx + 1 < N) v.y = deg[idx + 1];
    if (idx + 2 < N) v.z = deg[idx + 2];
    if (idx + 3 < N) v.w = deg[idx + 3];
  }
  int s = v.x + v.y + v.z + v.w;
  int lane = t & 63, w = t >> 6;
  int sc = s;
#pragma unroll
  for (int off = 1; off < 64; off <<= 1) {
    int u = __shfl_up(sc, off);
    if (lane >= off) sc += u;
  }
  if (lane == 63) woff[w] = sc;
  __syncthreads();
  int boff = boff_sh;
#pragma unroll
  for (int i = 0; i < 4; ++i)
    if (i < w) boff += woff[i];
  int ex = boff + sc - s;
  if (idx + 3 < N) {
    int4 o;
    o.x = ex;
    o.y = ex + v.x;
    o.z = ex + v.x + v.y;
    o.w = ex + v.x + v.y + v.z;
    *reinterpret_cast<int4*>(row_start + idx) = o;
  } else {
    if (idx + 0 < N) row_start[idx + 0] = ex;
    if (idx + 1 < N) row_start[idx + 1] = ex + v.x;
    if (idx + 2 < N) row_start[idx + 2] = ex + v.x + v.y;
    if (idx + 3 < N) row_start[idx + 3] = ex + v.x + v.y + v.z;
  }
}

// ---- aggregation: pre[n] = bf16( (1+eps)*h[n] + sum_{s in in(n)} h[s] ) ----
template <int D>
__global__ __launch_bounds__(256) void aggregate(const unsigned short* __restrict__ hb,
                                                 const int* __restrict__ csr,
                                                 const int* __restrict__ row_start,
                                                 const int* __restrict__ deg,
                                                 const float* __restrict__ eps_all,
                                                 int layer,
                                                 unsigned short* __restrict__ pre,
                                                 int N) {
  constexpr int PL = D / 32;
  const int half = threadIdx.x >> 5;
  const int lane = threadIdx.x & 31;
  const int node = blockIdx.x * 8 + half;
  if (node >= N) return;

  const int start = row_start[node];
  const int cnt = deg[node];
  const float epsv = 1.0f + eps_all[layer];

  float acc[PL];
#pragma unroll
  for (int j = 0; j < PL; ++j) acc[j] = 0.0f;

  if (D == 256) {
    uint4 su = *reinterpret_cast<const uint4*>(hb + (size_t)node * D + lane * 8);
    for (int base = 0; base < cnt; base += 32) {
      int m = cnt - base;
      if (m > 32) m = 32;
      int idx = (lane < m) ? csr[start + base + lane] : 0;
      int i = 0;
      for (; i + 8 <= m; i += 8) {
        uint4 q[8];
#pragma unroll
        for (int r = 0; r < 8; ++r) {
          int s = __shfl(idx, i + r, 32);
          q[r] = *reinterpret_cast<const uint4*>(hb + (size_t)s * D + lane * 8);
        }
#pragma unroll
        for (int r = 0; r < 8; ++r) {
          addbf2(acc[0], acc[1], q[r].x);
          addbf2(acc[2], acc[3], q[r].y);
          addbf2(acc[4], acc[5], q[r].z);
          addbf2(acc[6], acc[7], q[r].w);
        }
      }
      for (; i + 4 <= m; i += 4) {
        uint4 q[4];
#pragma unroll
        for (int r = 0; r < 4; ++r) {
          int s = __shfl(idx, i + r, 32);
          q[r] = *reinterpret_cast<const uint4*>(hb + (size_t)s * D + lane * 8);
        }
#pragma unroll
        for (int r = 0; r < 4; ++r) {
          addbf2(acc[0], acc[1], q[r].x);
          addbf2(acc[2], acc[3], q[r].y);
          addbf2(acc[4], acc[5], q[r].z);
          addbf2(acc[6], acc[7], q[r].w);
        }
      }
      for (; i < m; ++i) {
        int s = __shfl(idx, i, 32);
        uint4 q = *reinterpret_cast<const uint4*>(hb + (size_t)s * D + lane * 8);
        addbf2(acc[0], acc[1], q.x);
        addbf2(acc[2], acc[3], q.y);
        addbf2(acc[4], acc[5], q.z);
        addbf2(acc[6], acc[7], q.w);
      }
    }
    addbf2s(acc[0], acc[1], su.x, epsv);
    addbf2s(acc[2], acc[3], su.y, epsv);
    addbf2s(acc[4], acc[5], su.z, epsv);
    addbf2s(acc[6], acc[7], su.w, epsv);
    uint4 o;
    o.x = packbf(acc[0], acc[1]);
    o.y = packbf(acc[2], acc[3]);
    o.z = packbf(acc[4], acc[5]);
    o.w = packbf(acc[6], acc[7]);
    *reinterpret_cast<uint4*>(pre + (size_t)node * D + lane * 8) = o;
  } else {  // D == 128
    uint2 su = *reinterpret_cast<const uint2*>(hb + (size_t)node * D + lane * 4);
    for (int base = 0; base < cnt; base += 32) {
      int m = cnt - base;
      if (m > 32) m = 32;
      int idx = (lane < m) ? csr[start + base + lane] : 0;
      int i = 0;
      for (; i + 8 <= m; i += 8) {
        uint2 q[8];
#pragma unroll
        for (int r = 0; r < 8; ++r) {
          int s = __shfl(idx, i + r, 32);
          q[r] = *reinterpret_cast<const uint2*>(hb + (size_t)s * D + lane * 4);
        }
#pragma unroll
        for (int r = 0; r < 8; ++r) {
          addbf2(acc[0], acc[1], q[r].x);
          addbf2(acc[2], acc[3], q[r].y);
        }
      }
      for (; i + 4 <= m; i += 4) {
        uint2 q[4];
#pragma unroll
        for (int r = 0; r < 4; ++r) {
          int s = __shfl(idx, i + r, 32);
          q[r] = *reinterpret_cast<const uint2*>(hb + (size_t)s * D + lane * 4);
        }
#pragma unroll
        for (int r = 0; r < 4; ++r) {
          addbf2(acc[0], acc[1], q[r].x);
          addbf2(acc[2], acc[3], q[r].y);
        }
      }
      for (; i < m; ++i) {
        int s = __shfl(idx, i, 32);
        uint2 q = *reinterpret_cast<const uint2*>(hb + (size_t)s * D + lane * 4);
        addbf2(acc[0], acc[1], q.x);
        addbf2(acc[2], acc[3], q.y);
      }
    }
    addbf2s(acc[0], acc[1], su.x, epsv);
    addbf2s(acc[2], acc[3], su.y, epsv);
    uint2 o;
    o.x = packbf(acc[0], acc[1]);
    o.y = packbf(acc[2], acc[3]);
    *reinterpret_cast<uint2*>(pre + (size_t)node * D + lane * 4) = o;
  }
}

// ---- producer-consumer fused MLP: out = relu( relu(A@W0.T+b0) @ W1.T + b1 ) ----
// Block = 512 thr = 8 waves, one block per CU (grid 256), 32-row chunks,
// static stride (R13-proven; work-stealing atomics regressed).
// Waves 0-3 (producers): W0 quarter in regs; load A, MFMA, write mid to LDS.
// Waves 4-7 (consumers): W1 quarter in regs; MFMA LDS tile, store out.
template <int K0, bool OUT_BF16>
__global__ __launch_bounds__(512, 2) void mlp_fused(
    const unsigned short* __restrict__ Ap, const __hip_bfloat16* __restrict__ W0p,
    const float* __restrict__ b0, const __hip_bfloat16* __restrict__ W1p,
    const float* __restrict__ b1, void* __restrict__ Outp, int Nrows) {
  __shared__ unsigned short midb[2][32 * MID_STRIDE];  // 33.3 KB

  constexpr int NK0 = K0 / 32;
  constexpr int NK1 = D_H / 32;
  const int tid = threadIdx.x;
  const int wid = tid >> 6;        // 0..7
  const bool prod = (wid < 4);
  const int cg = wid & 3;          // col-group
  const int lane = tid & 63;
  const int l15 = lane & 15;
  const int kg = lane >> 4;
  const int col0 = cg * 64;
  const int nch = (Nrows + 31) >> 5;

  // register-resident W quarter + bias
  bf16x8 wfr[NK1][4];
  float bv[4];
  if (prod) {
    const unsigned short* Ws = (const unsigned short*)W0p;
#pragma unroll
    for (int ct = 0; ct < 4; ++ct) {
      const unsigned short* wrow = Ws + (size_t)(col0 + ct * 16 + l15) * K0 + kg * 8;
#pragma unroll
      for (int kk = 0; kk < NK0; ++kk)
        wfr[kk][ct] = *reinterpret_cast<const bf16x8*>(wrow + kk * 32);
      bv[ct] = b0[col0 + ct * 16 + l15];
    }
  } else {
    const unsigned short* Ws = (const unsigned short*)W1p;
#pragma unroll
    for (int ct = 0; ct < 4; ++ct) {
      const unsigned short* wrow = Ws + (size_t)(col0 + ct * 16 + l15) * D_H + kg * 8;
#pragma unroll
      for (int kk = 0; kk < NK1; ++kk)
        wfr[kk][ct] = *reinterpret_cast<const bf16x8*>(wrow + kk * 32);
      bv[ct] = b1[col0 + ct * 16 + l15];
    }
  }

  auto produce = [&](int c, unsigned short* buf) {
    const int r0 = c << 5;
    bf16x8 afr[NK0][2];
#pragma unroll
    for (int rt = 0; rt < 2; ++rt) {
      int row = r0 + rt * 16 + l15;
      if (row > Nrows - 1) row = Nrows - 1;  // clamp: dup rows feed masked C
      const unsigned short* ar = Ap + (size_t)row * K0 + kg * 8;
#pragma unroll
      for (int kk = 0; kk < NK0; ++kk)
        afr[kk][rt] = *reinterpret_cast<const bf16x8*>(ar + kk * 32);
    }
    f32x4 acc[2][4];
#pragma unroll
    for (int rt = 0; rt < 2; ++rt)
#pragma unroll
      for (int ct = 0; ct < 4; ++ct) acc[rt][ct] = 0.0f;
#pragma unroll
    for (int kk = 0; kk < NK0; ++kk)
#pragma unroll
      for (int rt = 0; rt < 2; ++rt)
#pragma unroll
        for (int ct = 0; ct < 4; ++ct)
          acc[rt][ct] = __builtin_amdgcn_mfma_f32_16x16x32_bf16(
              afr[kk][rt], wfr[kk][ct], acc[rt][ct], 0, 0, 0);
#pragma unroll
    for (int ct = 0; ct < 4; ++ct) {
      int col = col0 + ct * 16 + l15;
#pragma unroll
      for (int rt = 0; rt < 2; ++rt)
#pragma unroll
        for (int i = 0; i < 4; ++i) {
          int row_l = rt * 16 + kg * 4 + i;
          buf[row_l * MID_STRIDE + col] = bfbits(fmaxf(acc[rt][ct][i] + bv[ct], 0.0f));
        }
    }
  };

  auto consume = [&](int c, const unsigned short* buf) {
    const int r0 = c << 5;
    f32x4 acc[2][4];
#pragma unroll
    for (int rt = 0; rt < 2; ++rt)
#pragma unroll
      for (int ct = 0; ct < 4; ++ct) acc[rt][ct] = 0.0f;
#pragma unroll
    for (int kk = 0; kk < NK1; ++kk) {
      bf16x8 mfr[2];
#pragma unroll
      for (int rt = 0; rt < 2; ++rt)
        mfr[rt] = *reinterpret_cast<const bf16x8*>(
            buf + (rt * 16 + l15) * MID_STRIDE + kk * 32 + kg * 8);
#pragma unroll
      for (int rt = 0; rt < 2; ++rt)
#pragma unroll
        for (int ct = 0; ct < 4; ++ct)
          acc[rt][ct] = __builtin_amdgcn_mfma_f32_16x16x32_bf16(
              mfr[rt], wfr[kk][ct], acc[rt][ct], 0, 0, 0);
    }
#pragma unroll
    for (int ct = 0; ct < 4; ++ct) {
      int col = col0 + ct * 16 + l15;
#pragma unroll
      for (int rt = 0; rt < 2; ++rt)
#pragma unroll
        for (int i = 0; i < 4; ++i) {
          int row = r0 + rt * 16 + kg * 4 + i;
          if (row < Nrows) {
            float v = fmaxf(acc[rt][ct][i] + bv[ct], 0.0f);
            if (OUT_BF16)
              ((__hip_bfloat16*)Outp)[(size_t)row * D_H + col] = __float2bfloat16(v);
            else
              ((float*)Outp)[(size_t)row * D_H + col] = v;
          }
        }
    }
  };

  int c_pr = blockIdx.x;
  int c_co = blockIdx.x;
  int pb = 0;
  if (prod && c_pr < nch) produce(c_pr, midb[0]);
  __syncthreads();
  c_pr += gridDim.x;
  while (c_co < nch) {
    if (prod) {
      if (c_pr < nch) produce(c_pr, midb[pb ^ 1]);
    } else {
      consume(c_co, midb[pb]);
    }
    __syncthreads();
    pb ^= 1;
    c_pr += gridDim.x;
    c_co += gridDim.x;
  }
}

extern "C" void kernel_launch(void* const* d_in, const int* in_sizes, int n_in,
                              void* d_out, int out_size, void* d_ws, size_t ws_size,
                              hipStream_t stream) {
  const float* x = (const float*)d_in[0];
  const int* ei = (const int*)d_in[1];  // [2, E]: row0 = src, row1 = dst
  const float* eps_all = (const float*)d_in[2];
  const float* w0_l0 = (const float*)d_in[3];
  const float* b0_l0 = (const float*)d_in[4];
  const float* w1_l0 = (const float*)d_in[5];
  const float* b1_l0 = (const float*)d_in[6];
  const float* w0_rest = (const float*)d_in[7];
  const float* b0_rest = (const float*)d_in[8];
  const float* w1_rest = (const float*)d_in[9];
  const float* b1_rest = (const float*)d_in[10];

  const int N = in_sizes[0] / D_IN;  // 50000
  const int E = in_sizes[1] / 2;     // 800000
  const int NX = N * D_IN;           // x elements

  char* ws = (char*)d_ws;
  const size_t node_bf = (size_t)N * D_H * sizeof(unsigned short);  // 25.6 MB
  unsigned short* h = (unsigned short*)ws;                // layer outputs
  unsigned short* pre = (unsigned short*)(ws + node_bf);  // aggregate out
  unsigned short* xb = (unsigned short*)(ws + 2 * node_bf);  // x cast to bf16
  char* p = ws + 2 * node_bf + (size_t)NX * sizeof(unsigned short);
  __hip_bfloat16* wbf = (__hip_bfloat16*)p;
  p += 622592 * sizeof(__hip_bfloat16);
  int* deg = (int*)p;           // [N]
  int* cursor = deg + N;        // [N]
  int* row_start = cursor + N;  // [N]
  int* bsum = row_start + N;    // [64]
  int* csr = bsum + 64;         // [E]

  __hip_bfloat16* w0_l0_bf = wbf;
  __hip_bfloat16* w1_l0_bf = wbf + 32768;
  __hip_bfloat16* w0_rest_bf = wbf + 98304;
  __hip_bfloat16* w1_rest_bf = w0_rest_bf + 262144;

  conv_inputs<<<(NX + 622592 + 255) / 256, 256, 0, stream>>>(
      x, w0_l0, w1_l0, w0_rest, w1_rest, (__hip_bfloat16*)xb, wbf, NX);

  // CSR build
  const int nb = (N + 1023) / 1024;  // 49
  hipMemsetAsync(deg, 0, (size_t)2 * N * sizeof(int), stream);  // deg + cursor
  hist_kernel<<<8 * CSR_CHUNKS, 256, 0, stream>>>(ei, E, deg, N);
  block_sums<<<nb, 256, 0, stream>>>(deg, bsum, N);
  scan_apply<<<nb, 256, 0, stream>>>(deg, bsum, row_start, N);
  fill_kernel<<<8 * CSR_CHUNKS, 256, 0, stream>>>(ei, E, row_start, cursor, csr, N);

  const int mlpGrid = 256;  // one 8-wave block per CU
  const int aggBlocks = (N + 7) / 8;

  for (int layer = 0; layer < NLAYERS; ++layer) {
    const __hip_bfloat16* w0 =
        (layer == 0) ? w0_l0_bf : w0_rest_bf + (size_t)(layer - 1) * 65536;
    const float* b0 = (layer == 0) ? b0_l0 : b0_rest + (size_t)(layer - 1) * 256;
    const __hip_bfloat16* w1 =
        (layer == 0) ? w1_l0_bf : w1_rest_bf + (size_t)(layer - 1) * 65536;
    const float* b1 = (layer == 0) ? b1_l0 : b1_rest + (size_t)(layer - 1) * 256;

    if (layer == 0) {
      aggregate<D_IN><<<aggBlocks, 256, 0, stream>>>(xb, csr, row_start, deg,
                                                     eps_all, layer, pre, N);
      mlp_fused<D_IN, true><<<mlpGrid, 512, 0, stream>>>(pre, w0, b0, w1, b1, h, N);
    } else {
      aggregate<D_H><<<aggBlocks, 256, 0, stream>>>(h, csr, row_start, deg,
                                                    eps_all, layer, pre, N);
      if (layer == NLAYERS - 1)
        mlp_fused<D_H, false><<<mlpGrid, 512, 0, stream>>>(pre, w0, b0, w1, b1,
                                                           d_out, N);
      else
        mlp_fused<D_H, true><<<mlpGrid, 512, 0, stream>>>(pre, w0, b0, w1, b1, h, N);
    }
  }
}